// Round 1
// baseline (179.671 us; speedup 1.0000x reference)
//
#include <hip/hip_runtime.h>
#include <hip/hip_bf16.h>

#define GRID_RES 32
#define GRID_DIM 8
#define N_CELLS  (GRID_RES * GRID_DIM)   // 256
#define EMB_VOL  (GRID_DIM * GRID_DIM * GRID_DIM)  // 512

// One thread per point. 8-corner sparse trilinear interp + analytic gradient.
__global__ __launch_bounds__(256) void neural_poisson_interp(
    const float* __restrict__ positions,   // [N,3]
    const float* __restrict__ embeddings,  // [NUM_EMB, 512] (EMB_DIM==1)
    const int*   __restrict__ block_table, // [32,32,32]
    float* __restrict__ out_emb,           // [N]
    float* __restrict__ out_grad,          // [N,3]
    float* __restrict__ out_mask,          // [N] (1.0 / 0.0)
    int n)
{
    int i = blockIdx.x * blockDim.x + threadIdx.x;
    if (i >= n) return;

    float px = positions[3 * i + 0];
    float py = positions[3 * i + 1];
    float pz = positions[3 * i + 2];

    // world -> cell coords, matching reference op order: ((pos+1)*0.5)*(N_CELLS-1)
    float xcx = (px + 1.0f) * 0.5f * (float)(N_CELLS - 1);
    float xcy = (py + 1.0f) * 0.5f * (float)(N_CELLS - 1);
    float xcz = (pz + 1.0f) * 0.5f * (float)(N_CELLS - 1);

    float bfx = fminf(fmaxf(floorf(xcx), 0.0f), (float)(N_CELLS - 2));
    float bfy = fminf(fmaxf(floorf(xcy), 0.0f), (float)(N_CELLS - 2));
    float bfz = fminf(fmaxf(floorf(xcz), 0.0f), (float)(N_CELLS - 2));

    int bx = (int)bfx, by = (int)bfy, bz = (int)bfz;

    float fx = xcx - bfx;
    float fy = xcy - bfy;
    float fz = xcz - bfz;

    // weights and d(weight)/d(frac) signs per axis, indexed by corner bit
    float wx[2] = {1.0f - fx, fx};
    float wy[2] = {1.0f - fy, fy};
    float wz[2] = {1.0f - fz, fz};

    float acc = 0.0f;
    float gx = 0.0f, gy = 0.0f, gz = 0.0f;
    bool valid_all = true;

#pragma unroll
    for (int dx = 0; dx < 2; ++dx) {
        int cx  = bx + dx;
        int blkx = cx >> 3;
        int locx = cx & 7;
#pragma unroll
        for (int dy = 0; dy < 2; ++dy) {
            int cy  = by + dy;
            int blky = cy >> 3;
            int locy = cy & 7;
#pragma unroll
            for (int dz = 0; dz < 2; ++dz) {
                int cz  = bz + dz;
                int blkz = cz >> 3;
                int locz = cz & 7;

                int bidx = block_table[(blkx * GRID_RES + blky) * GRID_RES + blkz];
                if (bidx >= 0) {
                    int li = (locx * GRID_DIM + locy) * GRID_DIM + locz;
                    float e = embeddings[bidx * EMB_VOL + li];
                    float w = wx[dx] * wy[dy] * wz[dz];
                    acc += w * e;
                    float tgx = wy[dy] * wz[dz] * e;
                    float tgy = wx[dx] * wz[dz] * e;
                    float tgz = wx[dx] * wy[dy] * e;
                    gx += dx ? tgx : -tgx;
                    gy += dy ? tgy : -tgy;
                    gz += dz ? tgz : -tgz;
                } else {
                    valid_all = false;
                }
            }
        }
    }

    const float scale = 0.5f * (float)(N_CELLS - 1);  // 127.5
    out_emb[i] = acc;
    out_grad[3 * i + 0] = scale * gx;
    out_grad[3 * i + 1] = scale * gy;
    out_grad[3 * i + 2] = scale * gz;
    out_mask[i] = valid_all ? 1.0f : 0.0f;
}

extern "C" void kernel_launch(void* const* d_in, const int* in_sizes, int n_in,
                              void* d_out, int out_size, void* d_ws, size_t ws_size,
                              hipStream_t stream) {
    const float* positions  = (const float*)d_in[0];   // [N,3]
    const float* embeddings = (const float*)d_in[1];   // [NUM_EMB,512,1]
    const int*   block_table = (const int*)d_in[2];    // [32,32,32]

    int n = in_sizes[0] / 3;  // N_POINTS

    float* out = (float*)d_out;
    float* out_emb  = out;              // [N]
    float* out_grad = out + n;          // [N,3]
    float* out_mask = out + n + 3 * n;  // [N]

    int block = 256;
    int grid = (n + block - 1) / block;
    neural_poisson_interp<<<grid, block, 0, stream>>>(
        positions, embeddings, block_table, out_emb, out_grad, out_mask, n);
}

// Round 3
// 144.714 us; speedup vs baseline: 1.2416x; 1.2416x over previous
//
#include <hip/hip_runtime.h>
#include <hip/hip_bf16.h>

#define GRID_RES 32
#define GRID_DIM 8
#define N_CELLS  256
#define EMB_VOL  512   // GRID_DIM^3

// Branchless sparse trilinear interp + analytic gradient.
// 2 points per thread for memory-level parallelism: all 16 table loads issue
// independently, then all 16 embedding gathers (invalid corners clamp to
// block 0, masked out in the accumulate) -- no per-corner control flow.
__global__ __launch_bounds__(256) void neural_poisson_interp(
    const float* __restrict__ positions,   // [N,3]
    const float* __restrict__ embeddings,  // [NUM_EMB, 512]
    const int*   __restrict__ block_table, // [32,32,32]
    float* __restrict__ out,               // emb[N] | grad[N,3] | mask[N]
    int n, int half)
{
    int i = blockIdx.x * blockDim.x + threadIdx.x;
    if (i >= half) return;
    int j  = i + half;
    int jj = j < n ? j : (n - 1);   // clamp so point B's loads are always valid

    const int idx[2] = { i, jj };

    float wA [2][3];      // 1-frac per axis
    float wB [2][3];      // frac per axis
    int   bidx[2][8];
    int   li  [2][8];

#pragma unroll
    for (int p = 0; p < 2; ++p) {
        float px = positions[3 * idx[p] + 0];
        float py = positions[3 * idx[p] + 1];
        float pz = positions[3 * idx[p] + 2];

        float xc[3];
        xc[0] = (px + 1.0f) * 0.5f * (float)(N_CELLS - 1);
        xc[1] = (py + 1.0f) * 0.5f * (float)(N_CELLS - 1);
        xc[2] = (pz + 1.0f) * 0.5f * (float)(N_CELLS - 1);

        int base[3];
#pragma unroll
        for (int a = 0; a < 3; ++a) {
            float bf = fminf(fmaxf(floorf(xc[a]), 0.0f), (float)(N_CELLS - 2));
            float fr  = xc[a] - bf;
            wA[p][a] = 1.0f - fr;
            wB[p][a] = fr;
            base[a] = (int)bf;
        }

#pragma unroll
        for (int c = 0; c < 8; ++c) {
            int dx = (c >> 2) & 1, dy = (c >> 1) & 1, dz = c & 1;
            int cx = base[0] + dx, cy = base[1] + dy, cz = base[2] + dz;
            bidx[p][c] = block_table[((cx >> 3) * GRID_RES + (cy >> 3)) * GRID_RES
                                     + (cz >> 3)];
            li[p][c] = ((cx & 7) * GRID_DIM + (cy & 7)) * GRID_DIM + (cz & 7);
        }
    }

    // All 16 embedding gathers, branchless (clamped index).
    float e[2][8];
#pragma unroll
    for (int p = 0; p < 2; ++p)
#pragma unroll
        for (int c = 0; c < 8; ++c) {
            int b = bidx[p][c] > 0 ? bidx[p][c] : 0;
            e[p][c] = embeddings[b * EMB_VOL + li[p][c]];
        }

    const float scale = 0.5f * (float)(N_CELLS - 1);  // 127.5
    float* out_emb  = out;
    float* out_grad = out + n;
    float* out_mask = out + 4 * (size_t)n;

#pragma unroll
    for (int p = 0; p < 2; ++p) {
        float acc = 0.0f, gx = 0.0f, gy = 0.0f, gz = 0.0f;
        bool vall = true;
#pragma unroll
        for (int c = 0; c < 8; ++c) {
            int dx = (c >> 2) & 1, dy = (c >> 1) & 1, dz = c & 1;
            bool valid = bidx[p][c] >= 0;
            vall = vall && valid;
            float ev = valid ? e[p][c] : 0.0f;   // mask the gathered value
            float wx = dx ? wB[p][0] : wA[p][0];
            float wy = dy ? wB[p][1] : wA[p][1];
            float wz = dz ? wB[p][2] : wA[p][2];
            acc += wx * wy * wz * ev;
            float tgx = wy * wz * ev;
            float tgy = wx * wz * ev;
            float tgz = wx * wy * ev;
            gx += dx ? tgx : -tgx;
            gy += dy ? tgy : -tgy;
            gz += dz ? tgz : -tgz;
        }

        int o = idx[p];
        bool do_store = (p == 0) || (j < n);
        if (do_store) {
            out_emb[o]          = acc;
            out_grad[3 * o + 0] = scale * gx;
            out_grad[3 * o + 1] = scale * gy;
            out_grad[3 * o + 2] = scale * gz;
            out_mask[o]         = vall ? 1.0f : 0.0f;
        }
    }
}

extern "C" void kernel_launch(void* const* d_in, const int* in_sizes, int n_in,
                              void* d_out, int out_size, void* d_ws, size_t ws_size,
                              hipStream_t stream) {
    const float* positions   = (const float*)d_in[0];
    const float* embeddings  = (const float*)d_in[1];
    const int*   block_table = (const int*)d_in[2];

    int n = in_sizes[0] / 3;
    int half = (n + 1) / 2;

    float* out = (float*)d_out;

    int block = 256;
    int grid = (half + block - 1) / block;
    neural_poisson_interp<<<grid, block, 0, stream>>>(
        positions, embeddings, block_table, out, n, half);
}

// Round 4
// 139.769 us; speedup vs baseline: 1.2855x; 1.0354x over previous
//
#include <hip/hip_runtime.h>
#include <hip/hip_bf16.h>

#define GRID_RES 32
#define GRID_DIM 8
#define N_CELLS  256
#define EMB_VOL  512   // GRID_DIM^3
#define NPT      4     // points per thread

// Branchless sparse trilinear interp + analytic gradient.
// 4 adjacent points per thread: positions load as 3x float4, outputs store as
// float4. All 32 table loads issue independently, then all 32 embedding
// gathers (invalid corners clamp to block 0, masked in the accumulate).
__global__ __launch_bounds__(256) void neural_poisson_interp(
    const float* __restrict__ positions,   // [N,3]
    const float* __restrict__ embeddings,  // [NUM_EMB, 512]
    const int*   __restrict__ block_table, // [32,32,32]
    float* __restrict__ out,               // emb[N] | grad[N,3] | mask[N]
    int n)
{
    int t  = blockIdx.x * blockDim.x + threadIdx.x;
    int i0 = t * NPT;
    if (i0 >= n) return;
    bool full = (i0 + NPT <= n);

    float px[NPT], py[NPT], pz[NPT];
    if (full) {
        const float4* p4 = reinterpret_cast<const float4*>(positions + 3 * (size_t)i0);
        float4 A = p4[0], B = p4[1], C = p4[2];
        px[0] = A.x; py[0] = A.y; pz[0] = A.z;
        px[1] = A.w; py[1] = B.x; pz[1] = B.y;
        px[2] = B.z; py[2] = B.w; pz[2] = C.x;
        px[3] = C.y; py[3] = C.z; pz[3] = C.w;
    } else {
#pragma unroll
        for (int p = 0; p < NPT; ++p) {
            int ip = min(i0 + p, n - 1);
            px[p] = positions[3 * ip + 0];
            py[p] = positions[3 * ip + 1];
            pz[p] = positions[3 * ip + 2];
        }
    }

    float wA[NPT][3], wB[NPT][3];
    int   bidx[NPT][8];
    int   li  [NPT][8];

#pragma unroll
    for (int p = 0; p < NPT; ++p) {
        float xc[3];
        xc[0] = (px[p] + 1.0f) * 0.5f * (float)(N_CELLS - 1);
        xc[1] = (py[p] + 1.0f) * 0.5f * (float)(N_CELLS - 1);
        xc[2] = (pz[p] + 1.0f) * 0.5f * (float)(N_CELLS - 1);

        int base[3];
#pragma unroll
        for (int a = 0; a < 3; ++a) {
            float bf = fminf(fmaxf(floorf(xc[a]), 0.0f), (float)(N_CELLS - 2));
            float fr = xc[a] - bf;
            wA[p][a] = 1.0f - fr;
            wB[p][a] = fr;
            base[a] = (int)bf;
        }

#pragma unroll
        for (int c = 0; c < 8; ++c) {
            int dx = (c >> 2) & 1, dy = (c >> 1) & 1, dz = c & 1;
            int cx = base[0] + dx, cy = base[1] + dy, cz = base[2] + dz;
            bidx[p][c] = block_table[((cx >> 3) * GRID_RES + (cy >> 3)) * GRID_RES
                                     + (cz >> 3)];
            li[p][c] = ((cx & 7) * GRID_DIM + (cy & 7)) * GRID_DIM + (cz & 7);
        }
    }

    // All 32 embedding gathers, branchless (clamped index).
    float e[NPT][8];
#pragma unroll
    for (int p = 0; p < NPT; ++p)
#pragma unroll
        for (int c = 0; c < 8; ++c) {
            int b = bidx[p][c] > 0 ? bidx[p][c] : 0;
            e[p][c] = embeddings[b * EMB_VOL + li[p][c]];
        }

    const float scale = 0.5f * (float)(N_CELLS - 1);  // 127.5
    float acc[NPT], gxv[NPT], gyv[NPT], gzv[NPT], mk[NPT];

#pragma unroll
    for (int p = 0; p < NPT; ++p) {
        float a = 0.0f, gx = 0.0f, gy = 0.0f, gz = 0.0f;
        bool vall = true;
#pragma unroll
        for (int c = 0; c < 8; ++c) {
            int dx = (c >> 2) & 1, dy = (c >> 1) & 1, dz = c & 1;
            bool valid = bidx[p][c] >= 0;
            vall = vall && valid;
            float ev = valid ? e[p][c] : 0.0f;
            float wx = dx ? wB[p][0] : wA[p][0];
            float wy = dy ? wB[p][1] : wA[p][1];
            float wz = dz ? wB[p][2] : wA[p][2];
            a  += wx * wy * wz * ev;
            float tgx = wy * wz * ev;
            float tgy = wx * wz * ev;
            float tgz = wx * wy * ev;
            gx += dx ? tgx : -tgx;
            gy += dy ? tgy : -tgy;
            gz += dz ? tgz : -tgz;
        }
        acc[p] = a;
        gxv[p] = scale * gx;
        gyv[p] = scale * gy;
        gzv[p] = scale * gz;
        mk[p]  = vall ? 1.0f : 0.0f;
    }

    float* out_emb  = out;
    float* out_grad = out + (size_t)n;
    float* out_mask = out + 4 * (size_t)n;

    if (full) {
        *reinterpret_cast<float4*>(out_emb + i0) =
            make_float4(acc[0], acc[1], acc[2], acc[3]);
        float4* g4 = reinterpret_cast<float4*>(out_grad + 3 * (size_t)i0);
        g4[0] = make_float4(gxv[0], gyv[0], gzv[0], gxv[1]);
        g4[1] = make_float4(gyv[1], gzv[1], gxv[2], gyv[2]);
        g4[2] = make_float4(gzv[2], gxv[3], gyv[3], gzv[3]);
        *reinterpret_cast<float4*>(out_mask + i0) =
            make_float4(mk[0], mk[1], mk[2], mk[3]);
    } else {
#pragma unroll
        for (int p = 0; p < NPT; ++p) {
            int ip = i0 + p;
            if (ip < n) {
                out_emb[ip]           = acc[p];
                out_grad[3 * ip + 0]  = gxv[p];
                out_grad[3 * ip + 1]  = gyv[p];
                out_grad[3 * ip + 2]  = gzv[p];
                out_mask[ip]          = mk[p];
            }
        }
    }
}

extern "C" void kernel_launch(void* const* d_in, const int* in_sizes, int n_in,
                              void* d_out, int out_size, void* d_ws, size_t ws_size,
                              hipStream_t stream) {
    const float* positions   = (const float*)d_in[0];
    const float* embeddings  = (const float*)d_in[1];
    const int*   block_table = (const int*)d_in[2];

    int n = in_sizes[0] / 3;
    int nthreads = (n + NPT - 1) / NPT;

    float* out = (float*)d_out;

    int block = 256;
    int grid = (nthreads + block - 1) / block;
    neural_poisson_interp<<<grid, block, 0, stream>>>(
        positions, embeddings, block_table, out, n);
}

// Round 5
// 130.244 us; speedup vs baseline: 1.3795x; 1.0731x over previous
//
#include <hip/hip_runtime.h>
#include <hip/hip_bf16.h>

#define GRID_RES 32
#define GRID_DIM 8
#define N_CELLS  256
#define EMB_VOL  512   // GRID_DIM^3
#define NPT      4     // points per thread
#define BLOCK    512
#define TAB_N    (GRID_RES * GRID_RES * GRID_RES)   // 32768

// Sparse trilinear interp + analytic gradient, branchless, 4 pts/thread.
// Block table (128KB int32) staged into LDS as int16 (64KB): table lookups
// become ds_read (off the L1 transaction path -- the measured bottleneck).
__global__ __launch_bounds__(BLOCK) void neural_poisson_interp(
    const float* __restrict__ positions,   // [N,3]
    const float* __restrict__ embeddings,  // [NUM_EMB, 512]
    const int*   __restrict__ block_table, // [32,32,32]
    float* __restrict__ out,               // emb[N] | grad[N,3] | mask[N]
    int n)
{
    __shared__ short stab[TAB_N];          // 64 KB

    // ---- stage table: coalesced int4 reads, short4 LDS writes ----
    {
        const int4* t4 = reinterpret_cast<const int4*>(block_table);
        for (int k = threadIdx.x; k < TAB_N / 4; k += BLOCK) {
            int4 v = t4[k];
            short4 s;
            s.x = (short)v.x; s.y = (short)v.y; s.z = (short)v.z; s.w = (short)v.w;
            *reinterpret_cast<short4*>(&stab[4 * k]) = s;
        }
    }
    __syncthreads();

    int t  = blockIdx.x * blockDim.x + threadIdx.x;
    int i0 = t * NPT;
    if (i0 >= n) return;
    bool full = (i0 + NPT <= n);

    float px[NPT], py[NPT], pz[NPT];
    if (full) {
        const float4* p4 = reinterpret_cast<const float4*>(positions + 3 * (size_t)i0);
        float4 A = p4[0], B = p4[1], C = p4[2];
        px[0] = A.x; py[0] = A.y; pz[0] = A.z;
        px[1] = A.w; py[1] = B.x; pz[1] = B.y;
        px[2] = B.z; py[2] = B.w; pz[2] = C.x;
        px[3] = C.y; py[3] = C.z; pz[3] = C.w;
    } else {
#pragma unroll
        for (int p = 0; p < NPT; ++p) {
            int ip = min(i0 + p, n - 1);
            px[p] = positions[3 * ip + 0];
            py[p] = positions[3 * ip + 1];
            pz[p] = positions[3 * ip + 2];
        }
    }

    float wA[NPT][3], wB[NPT][3];
    int   bidx[NPT][8];
    int   li  [NPT][8];

#pragma unroll
    for (int p = 0; p < NPT; ++p) {
        float xc[3];
        xc[0] = (px[p] + 1.0f) * 0.5f * (float)(N_CELLS - 1);
        xc[1] = (py[p] + 1.0f) * 0.5f * (float)(N_CELLS - 1);
        xc[2] = (pz[p] + 1.0f) * 0.5f * (float)(N_CELLS - 1);

        int base[3];
#pragma unroll
        for (int a = 0; a < 3; ++a) {
            float bf = fminf(fmaxf(floorf(xc[a]), 0.0f), (float)(N_CELLS - 2));
            float fr = xc[a] - bf;
            wA[p][a] = 1.0f - fr;
            wB[p][a] = fr;
            base[a] = (int)bf;
        }

#pragma unroll
        for (int c = 0; c < 8; ++c) {
            int dx = (c >> 2) & 1, dy = (c >> 1) & 1, dz = c & 1;
            int cx = base[0] + dx, cy = base[1] + dy, cz = base[2] + dz;
            bidx[p][c] = stab[((cx >> 3) * GRID_RES + (cy >> 3)) * GRID_RES
                              + (cz >> 3)];
            li[p][c] = ((cx & 7) * GRID_DIM + (cy & 7)) * GRID_DIM + (cz & 7);
        }
    }

    // All 32 embedding gathers, branchless (clamped index).
    float e[NPT][8];
#pragma unroll
    for (int p = 0; p < NPT; ++p)
#pragma unroll
        for (int c = 0; c < 8; ++c) {
            int b = bidx[p][c] > 0 ? bidx[p][c] : 0;
            e[p][c] = embeddings[b * EMB_VOL + li[p][c]];
        }

    const float scale = 0.5f * (float)(N_CELLS - 1);  // 127.5
    float acc[NPT], gxv[NPT], gyv[NPT], gzv[NPT], mk[NPT];

#pragma unroll
    for (int p = 0; p < NPT; ++p) {
        float a = 0.0f, gx = 0.0f, gy = 0.0f, gz = 0.0f;
        bool vall = true;
#pragma unroll
        for (int c = 0; c < 8; ++c) {
            int dx = (c >> 2) & 1, dy = (c >> 1) & 1, dz = c & 1;
            bool valid = bidx[p][c] >= 0;
            vall = vall && valid;
            float ev = valid ? e[p][c] : 0.0f;
            float wx = dx ? wB[p][0] : wA[p][0];
            float wy = dy ? wB[p][1] : wA[p][1];
            float wz = dz ? wB[p][2] : wA[p][2];
            a  += wx * wy * wz * ev;
            float tgx = wy * wz * ev;
            float tgy = wx * wz * ev;
            float tgz = wx * wy * ev;
            gx += dx ? tgx : -tgx;
            gy += dy ? tgy : -tgy;
            gz += dz ? tgz : -tgz;
        }
        acc[p] = a;
        gxv[p] = scale * gx;
        gyv[p] = scale * gy;
        gzv[p] = scale * gz;
        mk[p]  = vall ? 1.0f : 0.0f;
    }

    float* out_emb  = out;
    float* out_grad = out + (size_t)n;
    float* out_mask = out + 4 * (size_t)n;

    if (full) {
        *reinterpret_cast<float4*>(out_emb + i0) =
            make_float4(acc[0], acc[1], acc[2], acc[3]);
        float4* g4 = reinterpret_cast<float4*>(out_grad + 3 * (size_t)i0);
        g4[0] = make_float4(gxv[0], gyv[0], gzv[0], gxv[1]);
        g4[1] = make_float4(gyv[1], gzv[1], gxv[2], gyv[2]);
        g4[2] = make_float4(gzv[2], gxv[3], gyv[3], gzv[3]);
        *reinterpret_cast<float4*>(out_mask + i0) =
            make_float4(mk[0], mk[1], mk[2], mk[3]);
    } else {
#pragma unroll
        for (int p = 0; p < NPT; ++p) {
            int ip = i0 + p;
            if (ip < n) {
                out_emb[ip]          = acc[p];
                out_grad[3 * ip + 0] = gxv[p];
                out_grad[3 * ip + 1] = gyv[p];
                out_grad[3 * ip + 2] = gzv[p];
                out_mask[ip]         = mk[p];
            }
        }
    }
}

extern "C" void kernel_launch(void* const* d_in, const int* in_sizes, int n_in,
                              void* d_out, int out_size, void* d_ws, size_t ws_size,
                              hipStream_t stream) {
    const float* positions   = (const float*)d_in[0];
    const float* embeddings  = (const float*)d_in[1];
    const int*   block_table = (const int*)d_in[2];

    int n = in_sizes[0] / 3;
    int nthreads = (n + NPT - 1) / NPT;

    float* out = (float*)d_out;

    int grid = (nthreads + BLOCK - 1) / BLOCK;
    neural_poisson_interp<<<grid, BLOCK, 0, stream>>>(
        positions, embeddings, block_table, out, n);
}